// Round 11
// baseline (1381.383 us; speedup 1.0000x reference)
//
#include <hip/hip_runtime.h>

// SelfAttention (channel attention, B=32, C=4096, C8=HW=512) on MI355X.
// QK merged triple GEMM (gemm_tri, gload_lds staging); E triple.
// V/out: 256^2 8-wave pipeline with frag read-ahead + counted lgkmcnt
// (r6 KTILE, clean test with r9 block order).

typedef _Float16 f16;
typedef _Float16 h8 __attribute__((ext_vector_type(8)));
typedef _Float16 h4 __attribute__((ext_vector_type(4)));
typedef _Float16 h2 __attribute__((ext_vector_type(2)));
typedef float fx4 __attribute__((ext_vector_type(4)));

#define CC  4096
#define C8  512
#define HWD 512
#define NB  32

__device__ __forceinline__ h8 ldfragC(const char* s, int row, int cb) {
  const int b = ((row << 7) | cb) ^ ((row & 7) << 4);   // XOR swizzle (T2)
  return *reinterpret_cast<const h8*>(s + b);
}

#define AS1C(p) ((const __attribute__((address_space(1))) unsigned int*)(p))
#define AS3(p)  ((__attribute__((address_space(3))) unsigned int*)(p))

// =================== 256^2 pipelined GEMM (non-triple) ======================
// C = A * B^T. A: M x K row-major (lda), B: N x K row-major (ldb).
// LDS: 2 buf x (A 32KB | B 32KB) = 128 KB dynamic. 1 block/CU, 8 waves.

#define STAGE_ALL(bufsel) { \
  char* la_ = smem + ((bufsel) << 16); \
  char* lb_ = la_ + 32768; \
  _Pragma("unroll") for (int q = 0; q < 4; ++q) { \
    __builtin_amdgcn_global_load_lds(AS1C(pA[q]), AS3(la_ + (q << 13) + w1024), 16, 0, 0); \
    __builtin_amdgcn_global_load_lds(AS1C(pB[q]), AS3(lb_ + (q << 13) + w1024), 16, 0, 0); \
    pA[q] += 128; pB[q] += 128; } }

#define STAGE2(bufsel, q) { \
  char* la_ = smem + ((bufsel) << 16); \
  char* lb_ = la_ + 32768; \
  __builtin_amdgcn_global_load_lds(AS1C(pA[q]), AS3(la_ + ((q) << 13) + w1024), 16, 0, 0); \
  __builtin_amdgcn_global_load_lds(AS1C(pB[q]), AS3(lb_ + ((q) << 13) + w1024), 16, 0, 0); \
  pA[q] += 128; pB[q] += 128; }

#define RD_A(dst, mh, kh, base) { \
  _Pragma("unroll") for (int f = 0; f < 4; ++f) \
    dst[f] = ldfragC(base, wr * 128 + (mh) * 64 + f * 16 + frow, (kh) * 64 + kq); }

#define RD_B(dst, kh, base) { \
  _Pragma("unroll") for (int g = 0; g < 4; ++g) \
    dst[g] = ldfragC(base, wc * 64 + g * 16 + frow, (kh) * 64 + kq); }

#define MMAQ(mh, av, bv) { \
  __builtin_amdgcn_s_setprio(1); \
  _Pragma("unroll") for (int f = 0; f < 4; ++f) \
  _Pragma("unroll") for (int g = 0; g < 4; ++g) \
    acc[(mh) * 4 + f][g] = __builtin_amdgcn_mfma_f32_16x16x32_f16( \
        av[f], bv[g], acc[(mh) * 4 + f][g], 0, 0, 0); \
  __builtin_amdgcn_s_setprio(0); }

// r6 KTILE: frags for phase p+1 read during phase p; counted lgkmcnt (DS
// retires in-order); one vmcnt(0) drain at PH3 (phase-locks blocks -> L2).
// Ledger: PH0 wait4 retires prev-PH3's 8; PH1 wait8 retires PH0's 4;
// PH2 wait4 retires PH1's 8; PH3 wait8 retires PH2's 4.
#define KTILE(cur, dost, dolast) { \
  const char* At = smem + ((cur) << 16); \
  const char* Bt = At + 32768; \
  const char* An = smem + (((cur) ^ 1) << 16); \
  const char* Bn = An + 32768; \
  /* PH0: MFMA(mh0,kh0); read a1(mh1,kh0) */ \
  __builtin_amdgcn_s_barrier(); \
  RD_A(a1, 1, 0, At) \
  if (dost) { STAGE2((cur) ^ 1, 0) STAGE2((cur) ^ 1, 1) } \
  asm volatile("s_waitcnt lgkmcnt(4)"); \
  __builtin_amdgcn_sched_barrier(0); \
  MMAQ(0, a0, bb0) \
  /* PH1: MFMA(mh1,kh0); read a0(mh0,kh1) + bb1(kh1) */ \
  __builtin_amdgcn_s_barrier(); \
  RD_A(a0, 0, 1, At) RD_B(bb1, 1, Bt) \
  if (dost) { STAGE2((cur) ^ 1, 2) STAGE2((cur) ^ 1, 3) } \
  asm volatile("s_waitcnt lgkmcnt(8)"); \
  __builtin_amdgcn_sched_barrier(0); \
  MMAQ(1, a1, bb0) \
  /* PH2: MFMA(mh0,kh1); read a1(mh1,kh1) */ \
  __builtin_amdgcn_s_barrier(); \
  RD_A(a1, 1, 1, At) \
  asm volatile("s_waitcnt lgkmcnt(4)"); \
  __builtin_amdgcn_sched_barrier(0); \
  MMAQ(0, a0, bb1) \
  /* PH3: MFMA(mh1,kh1); read next-tile a0(mh0,kh0) + bb0(kh0) */ \
  asm volatile("s_waitcnt vmcnt(0)" ::: "memory"); \
  __builtin_amdgcn_s_barrier(); \
  if (!(dolast)) { \
    RD_A(a0, 0, 0, An) RD_B(bb0, 0, Bn) \
    asm volatile("s_waitcnt lgkmcnt(8)"); \
  } else { \
    asm volatile("s_waitcnt lgkmcnt(0)"); \
  } \
  __builtin_amdgcn_sched_barrier(0); \
  MMAQ(1, a1, bb1) \
}

// EPI: 1 = f16+bias (V), 3 = gamma*acc+resid (out)
template<int EPI>
__global__ __launch_bounds__(512, 2) void gemm256(
    const f16* __restrict__ Ah, const f16* __restrict__ Bh,
    int lda, int ldb, long sAb, long sBb, long sCb, int ldc, int K,
    const float* __restrict__ bias, float* __restrict__ Cf, f16* __restrict__ Ch,
    const float* __restrict__ resid, const float* __restrict__ gam)
{
  extern __shared__ __align__(16) char smem[];
  // T1: bijective XCD swizzle (grid % 8 == 0), y-fastest local order (r9)
  const int F  = blockIdx.x;
  const int Vv = ((F & 7) << 7) | (F >> 3);
  const int bz = Vv >> 5;
  const int m0 = (Vv & 15) << 8;          // 16 M-tiles
  const int n0 = ((Vv >> 4) & 1) << 8;    // 2 N-tiles

  const int T = threadIdx.x;
  const int lane = T & 63;
  const int w = T >> 6;
  const int wr = w >> 2, wc = w & 3;      // 2x4 waves, each owns 128x64 of C
  const int frow = lane & 15;
  const int kq = (lane >> 4) << 4;
  const int w1024 = w << 10;

  // staging: thread T, quarter q writes LDS [q*8192 + T*16); inverse-swizzled source
  const int rr = T >> 3;
  const int corig = ((T & 7) << 4) ^ ((rr & 7) << 4);
  const char* pA[4];
  const char* pB[4];
#pragma unroll
  for (int q = 0; q < 4; ++q) {
    pA[q] = (const char*)(Ah + bz * sAb + (long)(m0 + q * 64 + rr) * lda) + corig;
    pB[q] = (const char*)(Bh + bz * sBb + (long)(n0 + q * 64 + rr) * ldb) + corig;
  }

  fx4 acc[8][4] = {};
  h8 a0[4], a1[4], bb0[4], bb1[4];
  const int nt = K >> 6;                   // even (64 or 8)

  // prologue: stage tile 0, drain, pre-read PH0 frags
  STAGE_ALL(0)
  asm volatile("s_waitcnt vmcnt(0)" ::: "memory");
  __builtin_amdgcn_s_barrier();
  RD_A(a0, 0, 0, smem) RD_B(bb0, 0, smem + 32768)

  for (int t = 0; t + 2 < nt; t += 2) {
    KTILE(0, 1, 0)
    KTILE(1, 1, 0)
  }
  KTILE(0, 1, 0)                           // t = nt-2 (stages tile nt-1)
  KTILE(1, 0, 1)                           // t = nt-1 (no stage, no read-ahead)

  // epilogue: C/D map col=lane&15, row=(lane>>4)*4+j
  const int cm = (lane >> 4) << 2;
  const int cn = lane & 15;
  const float g0 = (EPI == 3) ? gam[0] : 0.f;
#pragma unroll
  for (int fm = 0; fm < 8; ++fm) {
    const int gr0 = m0 + wr * 128 + fm * 16 + cm;
#pragma unroll
    for (int fn = 0; fn < 4; ++fn) {
      const int gc = n0 + wc * 64 + fn * 16 + cn;
#pragma unroll
      for (int j = 0; j < 4; ++j) {
        const long ci = bz * sCb + (long)(gr0 + j) * ldc + gc;
        if constexpr (EPI == 1) Ch[ci] = (f16)(acc[fm][fn][j] + bias[gr0 + j]);
        else                    Cf[ci] = g0 * acc[fm][fn][j] + resid[ci];
      }
    }
  }
}

// =================== triple-precision 128^2 GEMM (QK merged / E) ============
#define TSTG(p, off, ldB) { \
  _Pragma("unroll") for (int q = 0; q < 4; ++q) \
    __builtin_amdgcn_global_load_lds(AS1C((p) + (long)q * 32 * (ldB)), \
        AS3(smt + (off) + (q << 12) + (T << 4)), 16, 0, 0); \
  (p) += 128; }

// EPI: 0 = split(hi,lo)+bias (QK: bias rows<512, bias2 rows>=512), 2 = f32 (energy)
template<int EPI>
__global__ __launch_bounds__(256) void gemm_tri(
    const f16* __restrict__ Ah, const f16* __restrict__ Al,
    const f16* __restrict__ Bh, const f16* __restrict__ Bl,
    int K, int lda, int ldb, long sAb, long sBb, long sCb, int ldc,
    const float* __restrict__ bias, const float* __restrict__ bias2,
    float* __restrict__ Cf, f16* __restrict__ Ch, f16* __restrict__ Cl)
{
  __shared__ __align__(16) char smt[65536];   // [Ah|Bh|Al|Bl] 16KB each

  const int bz = blockIdx.z;
  const int m0 = blockIdx.y * 128, n0 = blockIdx.x * 128;
  const int T = threadIdx.x;
  const int lane = T & 63;
  const int wid  = T >> 6;
  const int wr = wid >> 1, wc = wid & 1;
  const int frow = lane & 15;
  const int kq = (lane >> 4) << 4;

  const int rr = T >> 3;
  const int cor = ((T & 7) << 4) ^ ((rr & 7) << 4);
  const long ldaB = (long)lda * 2, ldbB = (long)ldb * 2;
  const char* pAh = (const char*)(Ah + (long)bz * sAb + (long)(m0 + rr) * lda) + cor;
  const char* pAl = (const char*)(Al + (long)bz * sAb + (long)(m0 + rr) * lda) + cor;
  const char* pBh = (const char*)(Bh + (long)bz * sBb + (long)(n0 + rr) * ldb) + cor;
  const char* pBl = (const char*)(Bl + (long)bz * sBb + (long)(n0 + rr) * ldb) + cor;

  const char* sAh = smt;
  const char* sBh = smt + 16384;
  const char* sAl = smt + 32768;
  const char* sBl = smt + 49152;

  fx4 acc[4][4] = {};

  for (int k0 = 0; k0 < K; k0 += 64) {
    TSTG(pAh, 0, ldaB)
    TSTG(pBh, 16384, ldbB)
    TSTG(pAl, 32768, ldaB)
    TSTG(pBl, 49152, ldbB)
    asm volatile("s_waitcnt vmcnt(0)" ::: "memory");
    __syncthreads();
#pragma unroll
    for (int ks = 0; ks < 2; ++ks) {
      const int kb = ks * 64 + kq;
      h8 aH[4], bH[4], aL[4], bL[4];
#pragma unroll
      for (int f = 0; f < 4; ++f) {
        aH[f] = ldfragC(sAh, wr * 64 + f * 16 + frow, kb);
        bH[f] = ldfragC(sBh, wc * 64 + f * 16 + frow, kb);
        aL[f] = ldfragC(sAl, wr * 64 + f * 16 + frow, kb);
        bL[f] = ldfragC(sBl, wc * 64 + f * 16 + frow, kb);
      }
#pragma unroll
      for (int fm = 0; fm < 4; ++fm)
#pragma unroll
        for (int fn = 0; fn < 4; ++fn) {
          acc[fm][fn] = __builtin_amdgcn_mfma_f32_16x16x32_f16(aH[fm], bH[fn], acc[fm][fn], 0, 0, 0);
          acc[fm][fn] = __builtin_amdgcn_mfma_f32_16x16x32_f16(aH[fm], bL[fn], acc[fm][fn], 0, 0, 0);
          acc[fm][fn] = __builtin_amdgcn_mfma_f32_16x16x32_f16(aL[fm], bH[fn], acc[fm][fn], 0, 0, 0);
        }
    }
    __syncthreads();
  }

  const int cm = (lane >> 4) * 4;
  const int cn = lane & 15;
#pragma unroll
  for (int fm = 0; fm < 4; ++fm) {
    const int gr0 = m0 + wr * 64 + fm * 16 + cm;
#pragma unroll
    for (int fn = 0; fn < 4; ++fn) {
      const int gc = n0 + wc * 64 + fn * 16 + cn;
#pragma unroll
      for (int j = 0; j < 4; ++j) {
        const int gr = gr0 + j;
        const long ci = (long)bz * sCb + (long)gr * ldc + gc;
        float v = acc[fm][fn][j];
        if constexpr (EPI == 0) {
          v += (gr < 512) ? bias[gr] : bias2[gr - 512];
          const f16 h = (f16)v;
          Ch[ci] = h;
          Cl[ci] = (f16)(v - (float)h);
        } else {
          Cf[ci] = v;
        }
      }
    }
  }
}

// ---- x (b,c,l) f32 -> xT (b,l,c) f16 hi/lo; vectorized h2 stores ----
__global__ void transpose_split_k(const float* __restrict__ x, f16* __restrict__ xh, f16* __restrict__ xl) {
  __shared__ float t[32][33];
  const int l0 = blockIdx.x * 32, c0 = blockIdx.y * 32;
  const long bi = (long)blockIdx.z * CC * HWD;
  const long bo = (long)blockIdx.z * HWD * CC;
  const int tx = threadIdx.x, ty = threadIdx.y;   // 16 x 16
#pragma unroll
  for (int i = 0; i < 2; ++i)
#pragma unroll
    for (int j = 0; j < 2; ++j)
      t[ty + 16 * i][tx + 16 * j] = x[bi + (long)(c0 + ty + 16 * i) * HWD + l0 + tx + 16 * j];
  __syncthreads();
#pragma unroll
  for (int i = 0; i < 2; ++i) {
    const int l = ty + 16 * i;
    const float v0 = t[2 * tx][l], v1 = t[2 * tx + 1][l];
    const f16 h0 = (f16)v0, h1 = (f16)v1;
    const long o = bo + (long)(l0 + l) * CC + c0 + 2 * tx;
    h2 hh; hh[0] = h0; hh[1] = h1;
    h2 ll; ll[0] = (f16)(v0 - (float)h0); ll[1] = (f16)(v1 - (float)h1);
    *reinterpret_cast<h2*>(xh + o) = hh;
    *reinterpret_cast<h2*>(xl + o) = ll;
  }
}

// ---- fp32 -> f16 hi/lo split (elementwise) ----
template<bool HASLO>
__global__ void split_k(const float* __restrict__ in, f16* __restrict__ hi, f16* __restrict__ lo, long n) {
  const long i = ((long)blockIdx.x * blockDim.x + threadIdx.x) * 4;
  if (i >= n) return;
  const float4 v = *reinterpret_cast<const float4*>(in + i);
  const float vv[4] = {v.x, v.y, v.z, v.w};
  h4 h, l;
#pragma unroll
  for (int j = 0; j < 4; ++j) {
    const f16 hh = (f16)vv[j];
    h[j] = hh;
    l[j] = (f16)(vv[j] - (float)hh);
  }
  *reinterpret_cast<h4*>(hi + i) = h;
  if constexpr (HASLO) *reinterpret_cast<h4*>(lo + i) = l;
}

// ---- row softmax: E (rows of 512 f32) -> attn f16 ----
__global__ __launch_bounds__(256) void softmax_k(const float* __restrict__ E, f16* __restrict__ attn) {
  const int lane = threadIdx.x & 63;
  const int wid  = threadIdx.x >> 6;
  const long row = (long)blockIdx.x * 4 + wid;
  const float* e = E + row * 512;
  const float4 a = *reinterpret_cast<const float4*>(e + lane * 8);
  const float4 b = *reinterpret_cast<const float4*>(e + lane * 8 + 4);
  float vv[8] = {a.x, a.y, a.z, a.w, b.x, b.y, b.z, b.w};
  float m = vv[0];
#pragma unroll
  for (int i = 1; i < 8; ++i) m = fmaxf(m, vv[i]);
#pragma unroll
  for (int s = 32; s > 0; s >>= 1) m = fmaxf(m, __shfl_xor(m, s));
  float sum = 0.f;
  float ex[8];
#pragma unroll
  for (int i = 0; i < 8; ++i) { ex[i] = __expf(vv[i] - m); sum += ex[i]; }
#pragma unroll
  for (int s = 32; s > 0; s >>= 1) sum += __shfl_xor(sum, s);
  const float inv = 1.f / sum;
  h8 o;
#pragma unroll
  for (int i = 0; i < 8; ++i) o[i] = (f16)(ex[i] * inv);
  *reinterpret_cast<h8*>(attn + row * 512 + lane * 8) = o;
}

extern "C" void kernel_launch(void* const* d_in, const int* in_sizes, int n_in,
                              void* d_out, int out_size, void* d_ws, size_t ws_size,
                              hipStream_t stream) {
  const float* x  = (const float*)d_in[0];
  const float* Wq = (const float*)d_in[1];
  const float* bq = (const float*)d_in[2];
  const float* Wk = (const float*)d_in[3];
  const float* bk = (const float*)d_in[4];
  const float* Wv = (const float*)d_in[5];
  const float* bv = (const float*)d_in[6];
  const float* gm = (const float*)d_in[7];
  float* out = (float*)d_out;

  const size_t szXT  = (size_t)NB * HWD * CC;      // 67.1M f16
  const size_t szQK2 = (size_t)NB * 1024 * HWD;    // 16.8M f16 (Q+K packed)
  const size_t szW   = (size_t)C8 * CC;            // 2.1M f16
  const size_t szWv  = (size_t)CC * CC;            // 16.8M f16
  const size_t needBytes = (2 * szXT + 2 * szQK2 + 4 * szW + szWv) * sizeof(f16);
  if (ws_size < needBytes) return;

  f16* xT_h  = (f16*)d_ws;
  f16* xT_l  = xT_h + szXT;
  f16* v16   = xT_l;                // alias: V output reuses xT_lo (dead after QK)
  f16* qk_h  = xT_h + 2 * szXT;     // [b][1024][512]: rows 0-511 Q, 512-1023 K
  f16* qk_l  = qk_h + szQK2;
  f16* wqk_h = qk_l + szQK2;        // [Wq;Wk] hi, 1024 x 4096
  f16* wqk_l = wqk_h + 2 * szW;
  f16* attn  = wqk_h;               // alias: weights dead after QK GEMM
  f16* wv_h  = wqk_l + 2 * szW;
  float* E   = (float*)wv_h;        // alias: Wv dead after V GEMM

  // 1) weight splits
  split_k<true ><<<dim3((C8 * CC) / 1024), 256, 0, stream>>>(Wq, wqk_h, wqk_l, (long)C8 * CC);
  split_k<true ><<<dim3((C8 * CC) / 1024), 256, 0, stream>>>(Wk, wqk_h + szW, wqk_l + szW, (long)C8 * CC);
  split_k<false><<<dim3((CC * CC) / 1024), 256, 0, stream>>>(Wv, wv_h, nullptr, (long)CC * CC);
  // 2) x transpose + split
  transpose_split_k<<<dim3(HWD / 32, CC / 32, NB), dim3(16, 16), 0, stream>>>(x, xT_h, xT_l);
  // 3) QK = [Wq;Wk] * xf + [bq;bk]  (merged triple precision, split outputs)
  gemm_tri<0><<<dim3(4, 8, NB), 256, 0, stream>>>(wqk_h, wqk_l, xT_h, xT_l, CC, CC, CC,
      0L, (long)HWD * CC, (long)1024 * HWD, HWD, bq, bk, nullptr, qk_h, qk_l);
  // 4) V = Wv * xf + bv (read-ahead pipeline)
  gemm256<1><<<dim3(1024), 512, 131072, stream>>>(wv_h, xT_h, CC, CC,
      0L, (long)HWD * CC, (long)CC * HWD, HWD, CC, bv, nullptr, v16, nullptr, nullptr);
  // 5) E = Q * K^T (triple, f32 out; Q rows 0-511, K rows 512-1023 of qk)
  gemm_tri<2><<<dim3(4, 4, NB), 256, 0, stream>>>(qk_h, qk_l, qk_h + (size_t)512 * HWD, qk_l + (size_t)512 * HWD,
      HWD, HWD, HWD, (long)1024 * HWD, (long)1024 * HWD, (long)C8 * C8, C8,
      nullptr, nullptr, E, nullptr, nullptr);
  // 6) attn = softmax(E) rows
  softmax_k<<<dim3(NB * C8 / 4), 256, 0, stream>>>(E, attn);
  // 7) out = gamma * (V * attn^T) + x (read-ahead pipeline)
  gemm256<3><<<dim3(1024), 512, 131072, stream>>>(v16, attn, HWD, HWD,
      (long)CC * HWD, (long)C8 * HWD, (long)CC * HWD, HWD, C8, nullptr, out, nullptr, x, gm);
}

// Round 12
// 1337.525 us; speedup vs baseline: 1.0328x; 1.0328x over previous
//
#include <hip/hip_runtime.h>

// SelfAttention (channel attention, B=32, C=4096, C8=HW=512) on MI355X.
// QK merged triple GEMM (gemm_tri, gload_lds); E triple.
// V/out: 256^2 8-wave r4-phase pipeline at BK=32 / 64KB LDS -> 2 blocks/CU
// (cross-block overlap + intra-block phases; row-paired LDS swizzle).

typedef _Float16 f16;
typedef _Float16 h8 __attribute__((ext_vector_type(8)));
typedef _Float16 h4 __attribute__((ext_vector_type(4)));
typedef _Float16 h2 __attribute__((ext_vector_type(2)));
typedef float fx4 __attribute__((ext_vector_type(4)));

#define CC  4096
#define C8  512
#define HWD 512
#define NB  32

// 128B-row swizzled frag read (rows 0..127 direct; this variant used by tri)
__device__ __forceinline__ h8 ldfragC(const char* s, int row, int cb) {
  const int b = ((row << 7) | cb) ^ ((row & 7) << 4);
  return *reinterpret_cast<const h8*>(s + b);
}

// BK=32 row-paired layout: LDS row (r&127) holds tile-rows r and r+128.
// chunk index = (r>>7)*4 + kc (kc = lane's 16B k-chunk, 0..3), XOR (r&7).
__device__ __forceinline__ h8 ldfrag32(const char* s, int row, int kc) {
  const int chunk = ((row >> 7) << 2) | kc;
  const int b = ((row & 127) << 7) | ((chunk ^ (row & 7)) << 4);
  return *reinterpret_cast<const h8*>(s + b);
}

#define AS1C(p) ((const __attribute__((address_space(1))) unsigned int*)(p))
#define AS3(p)  ((__attribute__((address_space(3))) unsigned int*)(p))

// =================== 256^2 pipelined GEMM, BK=32 (non-triple) ===============
// C = A * B^T. A: M x K row-major (lda), B: N x K row-major (ldb).
// LDS: 2 buf x (A 16KB | B 16KB) = 64 KB dynamic -> 2 blocks/CU.

#define STGA32(bufsel, q) { \
  __builtin_amdgcn_global_load_lds(AS1C(pA[q]), \
      AS3(smem + ((bufsel) << 15) + ((q) << 13) + (T << 4)), 16, 0, 0); \
  pA[q] += 64; }
#define STGB32(bufsel, q) { \
  __builtin_amdgcn_global_load_lds(AS1C(pB[q]), \
      AS3(smem + ((bufsel) << 15) + 16384 + ((q) << 13) + (T << 4)), 16, 0, 0); \
  pB[q] += 64; }

#define RD_A32(dst, mh) { \
  _Pragma("unroll") for (int f = 0; f < 4; ++f) \
    dst[f] = ldfrag32(At, wr * 128 + (mh) * 64 + f * 16 + frow, kc); }

#define RD_B32(dst) { \
  _Pragma("unroll") for (int g = 0; g < 4; ++g) \
    dst[g] = ldfrag32(Bt, wc * 64 + g * 16 + frow, kc); }

#define MMA16(hm, av, bv) \
  __builtin_amdgcn_s_setprio(1); \
  _Pragma("unroll") for (int f = 0; f < 4; ++f) \
  _Pragma("unroll") for (int g = 0; g < 4; ++g) \
    acc[(hm) * 4 + f][g] = __builtin_amdgcn_mfma_f32_16x16x32_f16( \
        av[f], bv[g], acc[(hm) * 4 + f][g], 0, 0, 0); \
  __builtin_amdgcn_s_setprio(0);

// r4 barrier skeleton, 2 phases per K-tile(32). Per-tile vmcnt(0) drain
// preserves block phase-lock (L2); cross-block overlap hides the stalls.
#define KTILE32(cur, DOSTAGE) { \
  const bool dost_ = (DOSTAGE); \
  const char* At = smem + ((cur) << 15); \
  const char* Bt = At + 16384; \
  h8 a0[4], a1[4], b0[4]; \
  asm volatile("s_waitcnt vmcnt(0)" ::: "memory"); \
  __builtin_amdgcn_s_barrier(); \
  /* P1: mh0 */ \
  RD_A32(a0, 0) RD_B32(b0) \
  if (dost_) { STGA32((cur) ^ 1, 0) STGB32((cur) ^ 1, 0) } \
  __builtin_amdgcn_s_barrier(); \
  asm volatile("s_waitcnt lgkmcnt(0)"); \
  MMA16(0, a0, b0) \
  __builtin_amdgcn_s_barrier(); \
  /* P2: mh1 */ \
  RD_A32(a1, 1) \
  if (dost_) { STGA32((cur) ^ 1, 1) STGB32((cur) ^ 1, 1) } \
  __builtin_amdgcn_s_barrier(); \
  asm volatile("s_waitcnt lgkmcnt(0)"); \
  MMA16(1, a1, b0) \
  __builtin_amdgcn_s_barrier(); \
}

// EPI: 1 = f16+bias (V), 3 = gamma*acc+resid (out)
template<int EPI>
__global__ __launch_bounds__(512, 2) void gemm256(
    const f16* __restrict__ Ah, const f16* __restrict__ Bh,
    int lda, int ldb, long sAb, long sBb, long sCb, int ldc, int K,
    const float* __restrict__ bias, float* __restrict__ Cf, f16* __restrict__ Ch,
    const float* __restrict__ resid, const float* __restrict__ gam)
{
  extern __shared__ __align__(16) char smem[];
  // T1: bijective XCD swizzle (grid % 8 == 0), y-fastest local order
  const int F  = blockIdx.x;
  const int Vv = ((F & 7) << 7) | (F >> 3);
  const int bz = Vv >> 5;
  const int m0 = (Vv & 15) << 8;          // 16 M-tiles
  const int n0 = ((Vv >> 4) & 1) << 8;    // 2 N-tiles

  const int T = threadIdx.x;
  const int lane = T & 63;
  const int w = T >> 6;
  const int wr = w >> 2, wc = w & 3;      // 2x4 waves, each owns 128x64 of C
  const int frow = lane & 15;
  const int kc = lane >> 4;               // 16B k-chunk (BK=32 -> 4 chunks)

  // staging: q in {0,1}: LDS-row R = q*64 + (T>>3); chunk_orig = (T&7)^(R&7);
  // tile-row = R + 128*(chunk_orig>=4); k-chunk = chunk_orig&3.
  const int Rl = (T >> 3) & 7;            // R&7 (q*64 doesn't affect low bits)
  const int corig = (T & 7) ^ Rl;
  const char* pA[2];
  const char* pB[2];
#pragma unroll
  for (int q = 0; q < 2; ++q) {
    const int tr = q * 64 + (T >> 3) + ((corig >> 2) << 7);
    pA[q] = (const char*)(Ah + bz * sAb + (long)(m0 + tr) * lda) + (corig & 3) * 16;
    pB[q] = (const char*)(Bh + bz * sBb + (long)(n0 + tr) * ldb) + (corig & 3) * 16;
  }

  fx4 acc[8][4] = {};
  const int nt = K >> 5;                   // 128 (V) or 16 (out), even

  STGA32(0, 0) STGA32(0, 1) STGB32(0, 0) STGB32(0, 1)   // tile 0 -> buf 0
  for (int t = 0; t < nt; t += 2) {
    KTILE32(0, t + 1 < nt)
    KTILE32(1, t + 2 < nt)
  }

  // epilogue: C/D map col=lane&15, row=(lane>>4)*4+j
  const int cm = (lane >> 4) << 2;
  const int cn = lane & 15;
  const float g0 = (EPI == 3) ? gam[0] : 0.f;
#pragma unroll
  for (int fm = 0; fm < 8; ++fm) {
    const int gr0 = m0 + wr * 128 + fm * 16 + cm;
#pragma unroll
    for (int fn = 0; fn < 4; ++fn) {
      const int gc = n0 + wc * 64 + fn * 16 + cn;
#pragma unroll
      for (int j = 0; j < 4; ++j) {
        const long ci = bz * sCb + (long)(gr0 + j) * ldc + gc;
        if constexpr (EPI == 1) Ch[ci] = (f16)(acc[fm][fn][j] + bias[gr0 + j]);
        else                    Cf[ci] = g0 * acc[fm][fn][j] + resid[ci];
      }
    }
  }
}

// =================== triple-precision 128^2 GEMM (QK merged / E) ============
#define TSTG(p, off, ldB) { \
  _Pragma("unroll") for (int q = 0; q < 4; ++q) \
    __builtin_amdgcn_global_load_lds(AS1C((p) + (long)q * 32 * (ldB)), \
        AS3(smt + (off) + (q << 12) + (T << 4)), 16, 0, 0); \
  (p) += 128; }

// EPI: 0 = split(hi,lo)+bias (QK: bias rows<512, bias2 rows>=512), 2 = f32 (energy)
template<int EPI>
__global__ __launch_bounds__(256) void gemm_tri(
    const f16* __restrict__ Ah, const f16* __restrict__ Al,
    const f16* __restrict__ Bh, const f16* __restrict__ Bl,
    int K, int lda, int ldb, long sAb, long sBb, long sCb, int ldc,
    const float* __restrict__ bias, const float* __restrict__ bias2,
    float* __restrict__ Cf, f16* __restrict__ Ch, f16* __restrict__ Cl)
{
  __shared__ __align__(16) char smt[65536];   // [Ah|Bh|Al|Bl] 16KB each

  const int bz = blockIdx.z;
  const int m0 = blockIdx.y * 128, n0 = blockIdx.x * 128;
  const int T = threadIdx.x;
  const int lane = T & 63;
  const int wid  = T >> 6;
  const int wr = wid >> 1, wc = wid & 1;
  const int frow = lane & 15;
  const int kq = (lane >> 4) << 4;

  const int rr = T >> 3;
  const int cor = ((T & 7) << 4) ^ ((rr & 7) << 4);
  const long ldaB = (long)lda * 2, ldbB = (long)ldb * 2;
  const char* pAh = (const char*)(Ah + (long)bz * sAb + (long)(m0 + rr) * lda) + cor;
  const char* pAl = (const char*)(Al + (long)bz * sAb + (long)(m0 + rr) * lda) + cor;
  const char* pBh = (const char*)(Bh + (long)bz * sBb + (long)(n0 + rr) * ldb) + cor;
  const char* pBl = (const char*)(Bl + (long)bz * sBb + (long)(n0 + rr) * ldb) + cor;

  const char* sAh = smt;
  const char* sBh = smt + 16384;
  const char* sAl = smt + 32768;
  const char* sBl = smt + 49152;

  fx4 acc[4][4] = {};

  for (int k0 = 0; k0 < K; k0 += 64) {
    TSTG(pAh, 0, ldaB)
    TSTG(pBh, 16384, ldbB)
    TSTG(pAl, 32768, ldaB)
    TSTG(pBl, 49152, ldbB)
    asm volatile("s_waitcnt vmcnt(0)" ::: "memory");
    __syncthreads();
#pragma unroll
    for (int ks = 0; ks < 2; ++ks) {
      const int kb = ks * 64 + kq;
      h8 aH[4], bH[4], aL[4], bL[4];
#pragma unroll
      for (int f = 0; f < 4; ++f) {
        aH[f] = ldfragC(sAh, wr * 64 + f * 16 + frow, kb);
        bH[f] = ldfragC(sBh, wc * 64 + f * 16 + frow, kb);
        aL[f] = ldfragC(sAl, wr * 64 + f * 16 + frow, kb);
        bL[f] = ldfragC(sBl, wc * 64 + f * 16 + frow, kb);
      }
#pragma unroll
      for (int fm = 0; fm < 4; ++fm)
#pragma unroll
        for (int fn = 0; fn < 4; ++fn) {
          acc[fm][fn] = __builtin_amdgcn_mfma_f32_16x16x32_f16(aH[fm], bH[fn], acc[fm][fn], 0, 0, 0);
          acc[fm][fn] = __builtin_amdgcn_mfma_f32_16x16x32_f16(aH[fm], bL[fn], acc[fm][fn], 0, 0, 0);
          acc[fm][fn] = __builtin_amdgcn_mfma_f32_16x16x32_f16(aL[fm], bH[fn], acc[fm][fn], 0, 0, 0);
        }
    }
    __syncthreads();
  }

  const int cm = (lane >> 4) * 4;
  const int cn = lane & 15;
#pragma unroll
  for (int fm = 0; fm < 4; ++fm) {
    const int gr0 = m0 + wr * 64 + fm * 16 + cm;
#pragma unroll
    for (int fn = 0; fn < 4; ++fn) {
      const int gc = n0 + wc * 64 + fn * 16 + cn;
#pragma unroll
      for (int j = 0; j < 4; ++j) {
        const int gr = gr0 + j;
        const long ci = (long)bz * sCb + (long)gr * ldc + gc;
        float v = acc[fm][fn][j];
        if constexpr (EPI == 0) {
          v += (gr < 512) ? bias[gr] : bias2[gr - 512];
          const f16 h = (f16)v;
          Ch[ci] = h;
          Cl[ci] = (f16)(v - (float)h);
        } else {
          Cf[ci] = v;
        }
      }
    }
  }
}

// ---- x (b,c,l) f32 -> xT (b,l,c) f16 hi/lo; vectorized h2 stores ----
__global__ void transpose_split_k(const float* __restrict__ x, f16* __restrict__ xh, f16* __restrict__ xl) {
  __shared__ float t[32][33];
  const int l0 = blockIdx.x * 32, c0 = blockIdx.y * 32;
  const long bi = (long)blockIdx.z * CC * HWD;
  const long bo = (long)blockIdx.z * HWD * CC;
  const int tx = threadIdx.x, ty = threadIdx.y;   // 16 x 16
#pragma unroll
  for (int i = 0; i < 2; ++i)
#pragma unroll
    for (int j = 0; j < 2; ++j)
      t[ty + 16 * i][tx + 16 * j] = x[bi + (long)(c0 + ty + 16 * i) * HWD + l0 + tx + 16 * j];
  __syncthreads();
#pragma unroll
  for (int i = 0; i < 2; ++i) {
    const int l = ty + 16 * i;
    const float v0 = t[2 * tx][l], v1 = t[2 * tx + 1][l];
    const f16 h0 = (f16)v0, h1 = (f16)v1;
    const long o = bo + (long)(l0 + l) * CC + c0 + 2 * tx;
    h2 hh; hh[0] = h0; hh[1] = h1;
    h2 ll; ll[0] = (f16)(v0 - (float)h0); ll[1] = (f16)(v1 - (float)h1);
    *reinterpret_cast<h2*>(xh + o) = hh;
    *reinterpret_cast<h2*>(xl + o) = ll;
  }
}

// ---- fp32 -> f16 hi/lo split (elementwise) ----
template<bool HASLO>
__global__ void split_k(const float* __restrict__ in, f16* __restrict__ hi, f16* __restrict__ lo, long n) {
  const long i = ((long)blockIdx.x * blockDim.x + threadIdx.x) * 4;
  if (i >= n) return;
  const float4 v = *reinterpret_cast<const float4*>(in + i);
  const float vv[4] = {v.x, v.y, v.z, v.w};
  h4 h, l;
#pragma unroll
  for (int j = 0; j < 4; ++j) {
    const f16 hh = (f16)vv[j];
    h[j] = hh;
    l[j] = (f16)(vv[j] - (float)hh);
  }
  *reinterpret_cast<h4*>(hi + i) = h;
  if constexpr (HASLO) *reinterpret_cast<h4*>(lo + i) = l;
}

// ---- row softmax: E (rows of 512 f32) -> attn f16 ----
__global__ __launch_bounds__(256) void softmax_k(const float* __restrict__ E, f16* __restrict__ attn) {
  const int lane = threadIdx.x & 63;
  const int wid  = threadIdx.x >> 6;
  const long row = (long)blockIdx.x * 4 + wid;
  const float* e = E + row * 512;
  const float4 a = *reinterpret_cast<const float4*>(e + lane * 8);
  const float4 b = *reinterpret_cast<const float4*>(e + lane * 8 + 4);
  float vv[8] = {a.x, a.y, a.z, a.w, b.x, b.y, b.z, b.w};
  float m = vv[0];
#pragma unroll
  for (int i = 1; i < 8; ++i) m = fmaxf(m, vv[i]);
#pragma unroll
  for (int s = 32; s > 0; s >>= 1) m = fmaxf(m, __shfl_xor(m, s));
  float sum = 0.f;
  float ex[8];
#pragma unroll
  for (int i = 0; i < 8; ++i) { ex[i] = __expf(vv[i] - m); sum += ex[i]; }
#pragma unroll
  for (int s = 32; s > 0; s >>= 1) sum += __shfl_xor(sum, s);
  const float inv = 1.f / sum;
  h8 o;
#pragma unroll
  for (int i = 0; i < 8; ++i) o[i] = (f16)(ex[i] * inv);
  *reinterpret_cast<h8*>(attn + row * 512 + lane * 8) = o;
}

extern "C" void kernel_launch(void* const* d_in, const int* in_sizes, int n_in,
                              void* d_out, int out_size, void* d_ws, size_t ws_size,
                              hipStream_t stream) {
  const float* x  = (const float*)d_in[0];
  const float* Wq = (const float*)d_in[1];
  const float* bq = (const float*)d_in[2];
  const float* Wk = (const float*)d_in[3];
  const float* bk = (const float*)d_in[4];
  const float* Wv = (const float*)d_in[5];
  const float* bv = (const float*)d_in[6];
  const float* gm = (const float*)d_in[7];
  float* out = (float*)d_out;

  const size_t szXT  = (size_t)NB * HWD * CC;      // 67.1M f16
  const size_t szQK2 = (size_t)NB * 1024 * HWD;    // 16.8M f16 (Q+K packed)
  const size_t szW   = (size_t)C8 * CC;            // 2.1M f16
  const size_t szWv  = (size_t)CC * CC;            // 16.8M f16
  const size_t needBytes = (2 * szXT + 2 * szQK2 + 4 * szW + szWv) * sizeof(f16);
  if (ws_size < needBytes) return;

  f16* xT_h  = (f16*)d_ws;
  f16* xT_l  = xT_h + szXT;
  f16* v16   = xT_l;                // alias: V output reuses xT_lo (dead after QK)
  f16* qk_h  = xT_h + 2 * szXT;     // [b][1024][512]: rows 0-511 Q, 512-1023 K
  f16* qk_l  = qk_h + szQK2;
  f16* wqk_h = qk_l + szQK2;        // [Wq;Wk] hi, 1024 x 4096
  f16* wqk_l = wqk_h + 2 * szW;
  f16* attn  = wqk_h;               // alias: weights dead after QK GEMM
  f16* wv_h  = wqk_l + 2 * szW;
  float* E   = (float*)wv_h;        // alias: Wv dead after V GEMM

  // 1) weight splits
  split_k<true ><<<dim3((C8 * CC) / 1024), 256, 0, stream>>>(Wq, wqk_h, wqk_l, (long)C8 * CC);
  split_k<true ><<<dim3((C8 * CC) / 1024), 256, 0, stream>>>(Wk, wqk_h + szW, wqk_l + szW, (long)C8 * CC);
  split_k<false><<<dim3((CC * CC) / 1024), 256, 0, stream>>>(Wv, wv_h, nullptr, (long)CC * CC);
  // 2) x transpose + split
  transpose_split_k<<<dim3(HWD / 32, CC / 32, NB), dim3(16, 16), 0, stream>>>(x, xT_h, xT_l);
  // 3) QK = [Wq;Wk] * xf + [bq;bk]  (merged triple precision, split outputs)
  gemm_tri<0><<<dim3(4, 8, NB), 256, 0, stream>>>(wqk_h, wqk_l, xT_h, xT_l, CC, CC, CC,
      0L, (long)HWD * CC, (long)1024 * HWD, HWD, bq, bk, nullptr, qk_h, qk_l);
  // 4) V = Wv * xf + bv (BK=32 / 2-blocks-per-CU pipeline)
  gemm256<1><<<dim3(1024), 512, 65536, stream>>>(wv_h, xT_h, CC, CC,
      0L, (long)HWD * CC, (long)CC * HWD, HWD, CC, bv, nullptr, v16, nullptr, nullptr);
  // 5) E = Q * K^T (triple, f32 out; Q rows 0-511, K rows 512-1023 of qk)
  gemm_tri<2><<<dim3(4, 4, NB), 256, 0, stream>>>(qk_h, qk_l, qk_h + (size_t)512 * HWD, qk_l + (size_t)512 * HWD,
      HWD, HWD, HWD, (long)1024 * HWD, (long)1024 * HWD, (long)C8 * C8, C8,
      nullptr, nullptr, E, nullptr, nullptr);
  // 6) attn = softmax(E) rows
  softmax_k<<<dim3(NB * C8 / 4), 256, 0, stream>>>(E, attn);
  // 7) out = gamma * (V * attn^T) + x (BK=32 pipeline)
  gemm256<3><<<dim3(1024), 512, 65536, stream>>>(v16, attn, HWD, HWD,
      (long)CC * HWD, (long)C8 * HWD, (long)CC * HWD, HWD, C8, nullptr, out, nullptr, x, gm);
}

// Round 13
// 1254.432 us; speedup vs baseline: 1.1012x; 1.0662x over previous
//
#include <hip/hip_runtime.h>

// SelfAttention (channel attention, B=32, C=4096, C8=HW=512) on MI355X.
// Session-best configuration (round 9, 1255us):
//  - QK merged triple-precision GEMM (gemm_tri, gload_lds staging); E triple.
//  - V/out: 256^2 8-wave 4-phase r4-KTILE pipeline (531us, MfmaUtil 46.5%).
//  - h2-vectorized transpose/split; f16 hi/lo 3-MFMA emulation for Q/K/E.

typedef _Float16 f16;
typedef _Float16 h8 __attribute__((ext_vector_type(8)));
typedef _Float16 h4 __attribute__((ext_vector_type(4)));
typedef _Float16 h2 __attribute__((ext_vector_type(2)));
typedef float fx4 __attribute__((ext_vector_type(4)));

#define CC  4096
#define C8  512
#define HWD 512
#define NB  32

__device__ __forceinline__ h8 ldfragC(const char* s, int row, int cb) {
  const int b = ((row << 7) | cb) ^ ((row & 7) << 4);   // XOR swizzle (T2)
  return *reinterpret_cast<const h8*>(s + b);
}

#define AS1C(p) ((const __attribute__((address_space(1))) unsigned int*)(p))
#define AS3(p)  ((__attribute__((address_space(3))) unsigned int*)(p))

// =================== 256^2 pipelined GEMM (non-triple, r4-KTILE) ============
// C = A * B^T. A: M x K row-major (lda), B: N x K row-major (ldb).
// LDS: 2 buf x (A 32KB | B 32KB) = 128 KB dynamic.

#define STAGE_ALL(bufsel) { \
  char* la_ = smem + ((bufsel) << 16); \
  char* lb_ = la_ + 32768; \
  _Pragma("unroll") for (int q = 0; q < 4; ++q) { \
    __builtin_amdgcn_global_load_lds(AS1C(pA[q]), AS3(la_ + (q << 13) + w1024), 16, 0, 0); \
    __builtin_amdgcn_global_load_lds(AS1C(pB[q]), AS3(lb_ + (q << 13) + w1024), 16, 0, 0); \
    pA[q] += 128; pB[q] += 128; } }

#define STAGE2(bufsel, q) { \
  char* la_ = smem + ((bufsel) << 16); \
  char* lb_ = la_ + 32768; \
  __builtin_amdgcn_global_load_lds(AS1C(pA[q]), AS3(la_ + ((q) << 13) + w1024), 16, 0, 0); \
  __builtin_amdgcn_global_load_lds(AS1C(pB[q]), AS3(lb_ + ((q) << 13) + w1024), 16, 0, 0); \
  pA[q] += 128; pB[q] += 128; }

#define DSREADS_A(dst, hm, kh) \
  _Pragma("unroll") for (int f = 0; f < 4; ++f) \
    dst[f] = ldfragC(At, wr * 128 + (hm) * 64 + f * 16 + frow, (kh) * 64 + kq);

#define DSREADS_B(dst, kh) \
  _Pragma("unroll") for (int g = 0; g < 4; ++g) \
    dst[g] = ldfragC(Bt, wc * 64 + g * 16 + frow, (kh) * 64 + kq);

#define MMA16(hm, av, bv) \
  __builtin_amdgcn_s_setprio(1); \
  _Pragma("unroll") for (int f = 0; f < 4; ++f) \
  _Pragma("unroll") for (int g = 0; g < 4; ++g) \
    acc[(hm) * 4 + f][g] = __builtin_amdgcn_mfma_f32_16x16x32_f16( \
        av[f], bv[g], acc[(hm) * 4 + f][g], 0, 0, 0); \
  __builtin_amdgcn_s_setprio(0);

#define KTILE(cur, DOSTAGE) { \
  const bool dost_ = (DOSTAGE); \
  const char* At = smem + ((cur) << 16); \
  const char* Bt = At + 32768; \
  h8 a0[4], a1[4], b0[4], b1[4]; \
  asm volatile("s_waitcnt vmcnt(0)" ::: "memory"); \
  __builtin_amdgcn_s_barrier(); \
  /* P1 */ \
  DSREADS_A(a0, 0, 0) DSREADS_B(b0, 0) \
  if (dost_) { STAGE2((cur) ^ 1, 0) STAGE2((cur) ^ 1, 1) } \
  __builtin_amdgcn_s_barrier(); \
  asm volatile("s_waitcnt lgkmcnt(0)"); \
  MMA16(0, a0, b0) \
  __builtin_amdgcn_s_barrier(); \
  /* P2 */ \
  DSREADS_A(a1, 1, 0) \
  if (dost_) { STAGE2((cur) ^ 1, 2) STAGE2((cur) ^ 1, 3) } \
  __builtin_amdgcn_s_barrier(); \
  asm volatile("s_waitcnt lgkmcnt(0)"); \
  MMA16(1, a1, b0) \
  __builtin_amdgcn_s_barrier(); \
  /* P3 */ \
  DSREADS_A(a0, 0, 1) DSREADS_B(b1, 1) \
  __builtin_amdgcn_s_barrier(); \
  asm volatile("s_waitcnt lgkmcnt(0)"); \
  MMA16(0, a0, b1) \
  __builtin_amdgcn_s_barrier(); \
  /* P4 */ \
  DSREADS_A(a1, 1, 1) \
  __builtin_amdgcn_s_barrier(); \
  asm volatile("s_waitcnt lgkmcnt(0)"); \
  MMA16(1, a1, b1) \
  __builtin_amdgcn_s_barrier(); \
}

// EPI: 1 = f16+bias (V), 3 = gamma*acc+resid (out)
template<int EPI>
__global__ __launch_bounds__(512, 2) void gemm256(
    const f16* __restrict__ Ah, const f16* __restrict__ Bh,
    int lda, int ldb, long sAb, long sBb, long sCb, int ldc, int K,
    const float* __restrict__ bias, float* __restrict__ Cf, f16* __restrict__ Ch,
    const float* __restrict__ resid, const float* __restrict__ gam)
{
  extern __shared__ __align__(16) char smem[];
  // T1: bijective XCD swizzle (grid % 8 == 0), y-fastest local order
  const int F  = blockIdx.x;
  const int Vv = ((F & 7) << 7) | (F >> 3);
  const int bz = Vv >> 5;
  const int m0 = (Vv & 15) << 8;          // 16 M-tiles
  const int n0 = ((Vv >> 4) & 1) << 8;    // 2 N-tiles

  const int T = threadIdx.x;
  const int lane = T & 63;
  const int w = T >> 6;
  const int wr = w >> 2, wc = w & 3;      // 2x4 waves, each owns 128x64 of C
  const int frow = lane & 15;
  const int kq = (lane >> 4) << 4;
  const int w1024 = w << 10;

  // staging: thread T, quarter q writes LDS [q*8192 + T*16); inverse-swizzled source
  const int rr = T >> 3;
  const int corig = ((T & 7) << 4) ^ ((rr & 7) << 4);
  const char* pA[4];
  const char* pB[4];
#pragma unroll
  for (int q = 0; q < 4; ++q) {
    pA[q] = (const char*)(Ah + bz * sAb + (long)(m0 + q * 64 + rr) * lda) + corig;
    pB[q] = (const char*)(Bh + bz * sBb + (long)(n0 + q * 64 + rr) * ldb) + corig;
  }

  fx4 acc[8][4] = {};
  const int nt = K >> 6;                   // even (64 or 8)

  STAGE_ALL(0)                             // tile 0 -> buf 0
  for (int t = 0; t < nt; t += 2) {
    KTILE(0, t + 1 < nt)
    KTILE(1, t + 2 < nt)
  }

  // epilogue: C/D map col=lane&15, row=(lane>>4)*4+j
  const int cm = (lane >> 4) << 2;
  const int cn = lane & 15;
  const float g0 = (EPI == 3) ? gam[0] : 0.f;
#pragma unroll
  for (int fm = 0; fm < 8; ++fm) {
    const int gr0 = m0 + wr * 128 + fm * 16 + cm;
#pragma unroll
    for (int fn = 0; fn < 4; ++fn) {
      const int gc = n0 + wc * 64 + fn * 16 + cn;
#pragma unroll
      for (int j = 0; j < 4; ++j) {
        const long ci = bz * sCb + (long)(gr0 + j) * ldc + gc;
        if constexpr (EPI == 1) Ch[ci] = (f16)(acc[fm][fn][j] + bias[gr0 + j]);
        else                    Cf[ci] = g0 * acc[fm][fn][j] + resid[ci];
      }
    }
  }
}

// =================== triple-precision 128^2 GEMM (QK merged / E) ============
#define TSTG(p, off, ldB) { \
  _Pragma("unroll") for (int q = 0; q < 4; ++q) \
    __builtin_amdgcn_global_load_lds(AS1C((p) + (long)q * 32 * (ldB)), \
        AS3(smt + (off) + (q << 12) + (T << 4)), 16, 0, 0); \
  (p) += 128; }

// EPI: 0 = split(hi,lo)+bias (QK: bias rows<512, bias2 rows>=512), 2 = f32 (energy)
template<int EPI>
__global__ __launch_bounds__(256) void gemm_tri(
    const f16* __restrict__ Ah, const f16* __restrict__ Al,
    const f16* __restrict__ Bh, const f16* __restrict__ Bl,
    int K, int lda, int ldb, long sAb, long sBb, long sCb, int ldc,
    const float* __restrict__ bias, const float* __restrict__ bias2,
    float* __restrict__ Cf, f16* __restrict__ Ch, f16* __restrict__ Cl)
{
  __shared__ __align__(16) char smt[65536];   // [Ah|Bh|Al|Bl] 16KB each

  const int bz = blockIdx.z;
  const int m0 = blockIdx.y * 128, n0 = blockIdx.x * 128;
  const int T = threadIdx.x;
  const int lane = T & 63;
  const int wid  = T >> 6;
  const int wr = wid >> 1, wc = wid & 1;
  const int frow = lane & 15;
  const int kq = (lane >> 4) << 4;

  const int rr = T >> 3;
  const int cor = ((T & 7) << 4) ^ ((rr & 7) << 4);
  const long ldaB = (long)lda * 2, ldbB = (long)ldb * 2;
  const char* pAh = (const char*)(Ah + (long)bz * sAb + (long)(m0 + rr) * lda) + cor;
  const char* pAl = (const char*)(Al + (long)bz * sAb + (long)(m0 + rr) * lda) + cor;
  const char* pBh = (const char*)(Bh + (long)bz * sBb + (long)(n0 + rr) * ldb) + cor;
  const char* pBl = (const char*)(Bl + (long)bz * sBb + (long)(n0 + rr) * ldb) + cor;

  const char* sAh = smt;
  const char* sBh = smt + 16384;
  const char* sAl = smt + 32768;
  const char* sBl = smt + 49152;

  fx4 acc[4][4] = {};

  for (int k0 = 0; k0 < K; k0 += 64) {
    TSTG(pAh, 0, ldaB)
    TSTG(pBh, 16384, ldbB)
    TSTG(pAl, 32768, ldaB)
    TSTG(pBl, 49152, ldbB)
    asm volatile("s_waitcnt vmcnt(0)" ::: "memory");
    __syncthreads();
#pragma unroll
    for (int ks = 0; ks < 2; ++ks) {
      const int kb = ks * 64 + kq;
      h8 aH[4], bH[4], aL[4], bL[4];
#pragma unroll
      for (int f = 0; f < 4; ++f) {
        aH[f] = ldfragC(sAh, wr * 64 + f * 16 + frow, kb);
        bH[f] = ldfragC(sBh, wc * 64 + f * 16 + frow, kb);
        aL[f] = ldfragC(sAl, wr * 64 + f * 16 + frow, kb);
        bL[f] = ldfragC(sBl, wc * 64 + f * 16 + frow, kb);
      }
#pragma unroll
      for (int fm = 0; fm < 4; ++fm)
#pragma unroll
        for (int fn = 0; fn < 4; ++fn) {
          acc[fm][fn] = __builtin_amdgcn_mfma_f32_16x16x32_f16(aH[fm], bH[fn], acc[fm][fn], 0, 0, 0);
          acc[fm][fn] = __builtin_amdgcn_mfma_f32_16x16x32_f16(aH[fm], bL[fn], acc[fm][fn], 0, 0, 0);
          acc[fm][fn] = __builtin_amdgcn_mfma_f32_16x16x32_f16(aL[fm], bH[fn], acc[fm][fn], 0, 0, 0);
        }
    }
    __syncthreads();
  }

  const int cm = (lane >> 4) * 4;
  const int cn = lane & 15;
#pragma unroll
  for (int fm = 0; fm < 4; ++fm) {
    const int gr0 = m0 + wr * 64 + fm * 16 + cm;
#pragma unroll
    for (int fn = 0; fn < 4; ++fn) {
      const int gc = n0 + wc * 64 + fn * 16 + cn;
#pragma unroll
      for (int j = 0; j < 4; ++j) {
        const int gr = gr0 + j;
        const long ci = (long)bz * sCb + (long)gr * ldc + gc;
        float v = acc[fm][fn][j];
        if constexpr (EPI == 0) {
          v += (gr < 512) ? bias[gr] : bias2[gr - 512];
          const f16 h = (f16)v;
          Ch[ci] = h;
          Cl[ci] = (f16)(v - (float)h);
        } else {
          Cf[ci] = v;
        }
      }
    }
  }
}

// ---- x (b,c,l) f32 -> xT (b,l,c) f16 hi/lo; vectorized h2 stores ----
__global__ void transpose_split_k(const float* __restrict__ x, f16* __restrict__ xh, f16* __restrict__ xl) {
  __shared__ float t[32][33];
  const int l0 = blockIdx.x * 32, c0 = blockIdx.y * 32;
  const long bi = (long)blockIdx.z * CC * HWD;
  const long bo = (long)blockIdx.z * HWD * CC;
  const int tx = threadIdx.x, ty = threadIdx.y;   // 16 x 16
#pragma unroll
  for (int i = 0; i < 2; ++i)
#pragma unroll
    for (int j = 0; j < 2; ++j)
      t[ty + 16 * i][tx + 16 * j] = x[bi + (long)(c0 + ty + 16 * i) * HWD + l0 + tx + 16 * j];
  __syncthreads();
#pragma unroll
  for (int i = 0; i < 2; ++i) {
    const int l = ty + 16 * i;
    const float v0 = t[2 * tx][l], v1 = t[2 * tx + 1][l];
    const f16 h0 = (f16)v0, h1 = (f16)v1;
    const long o = bo + (long)(l0 + l) * CC + c0 + 2 * tx;
    h2 hh; hh[0] = h0; hh[1] = h1;
    h2 ll; ll[0] = (f16)(v0 - (float)h0); ll[1] = (f16)(v1 - (float)h1);
    *reinterpret_cast<h2*>(xh + o) = hh;
    *reinterpret_cast<h2*>(xl + o) = ll;
  }
}

// ---- fp32 -> f16 hi/lo split (elementwise) ----
template<bool HASLO>
__global__ void split_k(const float* __restrict__ in, f16* __restrict__ hi, f16* __restrict__ lo, long n) {
  const long i = ((long)blockIdx.x * blockDim.x + threadIdx.x) * 4;
  if (i >= n) return;
  const float4 v = *reinterpret_cast<const float4*>(in + i);
  const float vv[4] = {v.x, v.y, v.z, v.w};
  h4 h, l;
#pragma unroll
  for (int j = 0; j < 4; ++j) {
    const f16 hh = (f16)vv[j];
    h[j] = hh;
    l[j] = (f16)(vv[j] - (float)hh);
  }
  *reinterpret_cast<h4*>(hi + i) = h;
  if constexpr (HASLO) *reinterpret_cast<h4*>(lo + i) = l;
}

// ---- row softmax: E (rows of 512 f32) -> attn f16 ----
__global__ __launch_bounds__(256) void softmax_k(const float* __restrict__ E, f16* __restrict__ attn) {
  const int lane = threadIdx.x & 63;
  const int wid  = threadIdx.x >> 6;
  const long row = (long)blockIdx.x * 4 + wid;
  const float* e = E + row * 512;
  const float4 a = *reinterpret_cast<const float4*>(e + lane * 8);
  const float4 b = *reinterpret_cast<const float4*>(e + lane * 8 + 4);
  float vv[8] = {a.x, a.y, a.z, a.w, b.x, b.y, b.z, b.w};
  float m = vv[0];
#pragma unroll
  for (int i = 1; i < 8; ++i) m = fmaxf(m, vv[i]);
#pragma unroll
  for (int s = 32; s > 0; s >>= 1) m = fmaxf(m, __shfl_xor(m, s));
  float sum = 0.f;
  float ex[8];
#pragma unroll
  for (int i = 0; i < 8; ++i) { ex[i] = __expf(vv[i] - m); sum += ex[i]; }
#pragma unroll
  for (int s = 32; s > 0; s >>= 1) sum += __shfl_xor(sum, s);
  const float inv = 1.f / sum;
  h8 o;
#pragma unroll
  for (int i = 0; i < 8; ++i) o[i] = (f16)(ex[i] * inv);
  *reinterpret_cast<h8*>(attn + row * 512 + lane * 8) = o;
}

extern "C" void kernel_launch(void* const* d_in, const int* in_sizes, int n_in,
                              void* d_out, int out_size, void* d_ws, size_t ws_size,
                              hipStream_t stream) {
  const float* x  = (const float*)d_in[0];
  const float* Wq = (const float*)d_in[1];
  const float* bq = (const float*)d_in[2];
  const float* Wk = (const float*)d_in[3];
  const float* bk = (const float*)d_in[4];
  const float* Wv = (const float*)d_in[5];
  const float* bv = (const float*)d_in[6];
  const float* gm = (const float*)d_in[7];
  float* out = (float*)d_out;

  const size_t szXT  = (size_t)NB * HWD * CC;      // 67.1M f16
  const size_t szQK2 = (size_t)NB * 1024 * HWD;    // 16.8M f16 (Q+K packed)
  const size_t szW   = (size_t)C8 * CC;            // 2.1M f16
  const size_t szWv  = (size_t)CC * CC;            // 16.8M f16
  const size_t needBytes = (2 * szXT + 2 * szQK2 + 4 * szW + szWv) * sizeof(f16);
  if (ws_size < needBytes) return;

  f16* xT_h  = (f16*)d_ws;
  f16* xT_l  = xT_h + szXT;
  f16* v16   = xT_l;                // alias: V output reuses xT_lo (dead after QK)
  f16* qk_h  = xT_h + 2 * szXT;     // [b][1024][512]: rows 0-511 Q, 512-1023 K
  f16* qk_l  = qk_h + szQK2;
  f16* wqk_h = qk_l + szQK2;        // [Wq;Wk] hi, 1024 x 4096
  f16* wqk_l = wqk_h + 2 * szW;
  f16* attn  = wqk_h;               // alias: weights dead after QK GEMM
  f16* wv_h  = wqk_l + 2 * szW;
  float* E   = (float*)wv_h;        // alias: Wv dead after V GEMM

  // 1) weight splits
  split_k<true ><<<dim3((C8 * CC) / 1024), 256, 0, stream>>>(Wq, wqk_h, wqk_l, (long)C8 * CC);
  split_k<true ><<<dim3((C8 * CC) / 1024), 256, 0, stream>>>(Wk, wqk_h + szW, wqk_l + szW, (long)C8 * CC);
  split_k<false><<<dim3((CC * CC) / 1024), 256, 0, stream>>>(Wv, wv_h, nullptr, (long)CC * CC);
  // 2) x transpose + split
  transpose_split_k<<<dim3(HWD / 32, CC / 32, NB), dim3(16, 16), 0, stream>>>(x, xT_h, xT_l);
  // 3) QK = [Wq;Wk] * xf + [bq;bk]  (merged triple precision, split outputs)
  gemm_tri<0><<<dim3(4, 8, NB), 256, 0, stream>>>(wqk_h, wqk_l, xT_h, xT_l, CC, CC, CC,
      0L, (long)HWD * CC, (long)1024 * HWD, HWD, bq, bk, nullptr, qk_h, qk_l);
  // 4) V = Wv * xf + bv (r4-KTILE pipeline)
  gemm256<1><<<dim3(1024), 512, 131072, stream>>>(wv_h, xT_h, CC, CC,
      0L, (long)HWD * CC, (long)CC * HWD, HWD, CC, bv, nullptr, v16, nullptr, nullptr);
  // 5) E = Q * K^T (triple, f32 out; Q rows 0-511, K rows 512-1023 of qk)
  gemm_tri<2><<<dim3(4, 4, NB), 256, 0, stream>>>(qk_h, qk_l, qk_h + (size_t)512 * HWD, qk_l + (size_t)512 * HWD,
      HWD, HWD, HWD, (long)1024 * HWD, (long)1024 * HWD, (long)C8 * C8, C8,
      nullptr, nullptr, E, nullptr, nullptr);
  // 6) attn = softmax(E) rows
  softmax_k<<<dim3(NB * C8 / 4), 256, 0, stream>>>(E, attn);
  // 7) out = gamma * (V * attn^T) + x (r4-KTILE pipeline)
  gemm256<3><<<dim3(1024), 512, 131072, stream>>>(v16, attn, HWD, HWD,
      (long)CC * HWD, (long)C8 * HWD, (long)CC * HWD, HWD, C8, nullptr, out, nullptr, x, gm);
}